// Round 16
// baseline (31.310 us; speedup 1.0000x reference)
//
#include <hip/hip_runtime.h>
#include <hip/hip_bf16.h>
#include <math.h>

// Engram scan. Fast path: prove on-device that every step is a "create"
// (feedback == 0) and write zeros; exact sequential fallback otherwise.
//
// Soundness: n0==0 & B<=P => bank holds verbatim copies of earlier padrao
// rows and n<P always => every step creates unless a cos>=0.7 match exists
// among pairs (t, j<t). We flag at cos_q>=0.5 computed in fp8-e4m3 (RNE
// rel-err <=2^-4 => |cos_q-cos| <= ~0.135 with fp32 norms; 0.7-0.135 >
// 0.5 => conservative superset). Rows with any |x|>224 (e4m3 saturation)
// set guard[row] -> fallback. Also flagged: n0!=0, B>P. MFMA C-layout =
// m89 mapping; layout errors fail-safe (false flag -> exact fallback).
//
// r16 (r15 = 21.8us: memset-node removal gave -4.5us => ~4us/node):
// merge the fallback node into trimain via LAST-BLOCK-DONE ticket:
//  * prep block0 zero-inits done counter (plain store, stream-ordered).
//  * every trimain block: __threadfence(); ticket=atomicAdd(done,1);
//    the block with ticket==nblk-1 sees all flag-ORs (release via fence
//    before ticket, acquire via fence after) and runs the exact fallback
//    inline (256 threads). Deterministic: fallback executes exactly once.
//  * flag read atomically (device-scope, XCD-coherent).
// Fast path: 2 nodes (prep, trimain+fallback), was 3.

#define LIMIAR_SIM 0.7f
#define LIMIAR_NOVO 0.3f
#define LR 0.01f
#define EPSV 1e-8f
#define CHECK_THRESH 0.5f   // conservative vs 0.7 decision threshold
#define ABS_GUARD 224.0f    // |x| above this -> fp8 bound unsafe -> fallback

typedef __attribute__((ext_vector_type(4))) float f32x4;
typedef __attribute__((ext_vector_type(2))) long long i64x2;

// ---- exact sequential fallback body (NT threads; shared rv/ri provided) ----
__device__ void fallback_body(int NT, int tid,
    const float* __restrict__ padrao, const float* __restrict__ erro,
    const float* __restrict__ protos0, const float* __restrict__ forca0,
    const int* __restrict__ n0p, const float* __restrict__ gainp,
    float* __restrict__ out, const float* __restrict__ pn_arr,
    float* __restrict__ wprotos, float* __restrict__ wforca,
    float* __restrict__ wprotn, int B, int D, int P,
    float* rv, int* ri) {
    for (long long i = tid; i < (long long)P * D; i += NT) wprotos[i] = protos0[i];
    for (int i = tid; i < P; i += NT) wforca[i] = forca0[i];
    __syncthreads();
    for (int j = tid; j < P; j += NT) {
        const float* r = wprotos + (long long)j * D;
        float s = 0.0f;
        for (int k = 0; k < D; ++k) s += r[k] * r[k];
        wprotn[j] = fmaxf(sqrtf(s), EPSV);
    }
    int n = *n0p;
    float gain = *gainp;
    __syncthreads();
    for (int t = 0; t < B; ++t) {
        const float* p = padrao + (long long)t * D;
        float pn = pn_arr[t];
        float best = -INFINITY; int bidx = 0;
        for (int j = tid; j < n; j += NT) {
            const float* r = wprotos + (long long)j * D;
            float d = 0.0f;
            for (int k = 0; k < D; ++k) d += r[k] * p[k];
            float sim = d / (wprotn[j] * pn);
            if (sim > best) { best = sim; bidx = j; }
        }
        rv[tid] = best; ri[tid] = bidx;
        __syncthreads();
        for (int off = NT >> 1; off > 0; off >>= 1) {
            if (tid < off) {
                float ov = rv[tid + off]; int oi = ri[tid + off];
                if (ov > rv[tid] || (ov == rv[tid] && oi < ri[tid])) { rv[tid] = ov; ri[tid] = oi; }
            }
            __syncthreads();
        }
        float max_sim = rv[0]; int idx = ri[0];
        __syncthreads();
        float err = erro[t];
        bool is_empty = (n == 0);
        bool do_reinf = (!is_empty) && (max_sim >= LIMIAR_SIM);
        bool do_create = is_empty || ((!do_reinf) && ((err > LIMIAR_NOVO) || (n < P)));
        if (do_create) {
            int cidx = n;
            if (n >= P) {
                float bv = INFINITY; int bi = 0;
                for (int j = tid; j < P; j += NT) {
                    float f = wforca[j];
                    if (f < bv) { bv = f; bi = j; }
                }
                rv[tid] = bv; ri[tid] = bi;
                __syncthreads();
                for (int off = NT >> 1; off > 0; off >>= 1) {
                    if (tid < off) {
                        float ov = rv[tid + off]; int oi = ri[tid + off];
                        if (ov < rv[tid] || (ov == rv[tid] && oi < ri[tid])) { rv[tid] = ov; ri[tid] = oi; }
                    }
                    __syncthreads();
                }
                cidx = ri[0];
                __syncthreads();
            }
            float* dst = wprotos + (long long)cidx * D;
            float* o = out + (long long)t * D;
            for (int k = tid; k < D; k += NT) { dst[k] = p[k]; o[k] = 0.0f; }
            if (tid == 0) { wforca[cidx] = 1.0f; wprotn[cidx] = pn; }
            if (n < P) n = n + 1;
        } else if (do_reinf) {
            float* dst = wprotos + (long long)idx * D;
            float fr_new = wforca[idx] + LR;
            float* o = out + (long long)t * D;
            float s2 = 0.0f;
            for (int k = tid; k < D; k += NT) {
                float np_ = (1.0f - LR) * dst[k] + LR * p[k];
                dst[k] = np_;
                o[k] = (np_ - p[k]) * fr_new * gain;
                s2 += np_ * np_;
            }
            rv[tid] = s2;
            __syncthreads();
            for (int off = NT >> 1; off > 0; off >>= 1) {
                if (tid < off) rv[tid] += rv[tid + off];
                __syncthreads();
            }
            if (tid == 0) { wforca[idx] = fr_new; wprotn[idx] = fmaxf(sqrtf(rv[0]), EPSV); }
        } else {
            const float* src = wprotos + (long long)idx * D;
            float fr = wforca[idx];
            float* o = out + (long long)t * D;
            for (int k = tid; k < D; k += NT) o[k] = (src[k] - p[k]) * fr * gain;
        }
        __syncthreads();
    }
}

// -- kernel 1: row norms + packed fp8 convert + nt zero-fill + guard + done=0 --
__global__ __launch_bounds__(256) void k_prep(const float* __restrict__ padrao,
                                              int B, int D, float* __restrict__ pn,
                                              unsigned int* __restrict__ xq,
                                              int do_conv,
                                              f32x4* __restrict__ out4,
                                              long long n4z, int do_zero,
                                              unsigned int* __restrict__ flag,
                                              unsigned int* __restrict__ done,
                                              unsigned int* __restrict__ guard,
                                              const int* __restrict__ n0p,
                                              int force_flag) {
    __shared__ float red[4];
    __shared__ float redm[4];
    int row = blockIdx.x;
    if (do_zero) {
        long long chunk = (n4z + gridDim.x - 1) / gridDim.x;
        long long zb = (long long)row * chunk;
        long long ze = zb + chunk; if (ze > n4z) ze = n4z;
        f32x4 z = {0.f, 0.f, 0.f, 0.f};
        for (long long i = zb + threadIdx.x; i < ze; i += 256)
            __builtin_nontemporal_store(z, &out4[i]);
    }
    const float* r = padrao + (long long)row * D;
    float s = 0.0f, amax = 0.0f;
    if ((D & 3) == 0) {
        for (int k = threadIdx.x * 4; k < D; k += 1024) {
            float4 v = *(const float4*)(r + k);
            s += v.x * v.x + v.y * v.y + v.z * v.z + v.w * v.w;
            amax = fmaxf(amax, fmaxf(fmaxf(fabsf(v.x), fabsf(v.y)),
                                     fmaxf(fabsf(v.z), fabsf(v.w))));
            if (do_conv) {
                // fp8 pack, 4 elems -> u32 (RNE via v_cvt_pk_fp8_f32)
                int pk = 0;
                pk = __builtin_amdgcn_cvt_pk_fp8_f32(v.x, v.y, pk, false);
                pk = __builtin_amdgcn_cvt_pk_fp8_f32(v.z, v.w, pk, true);
                // slot permutation: chunk c=k>>3 (8 fp8), s=c>>3, j=c&7
                // slot = 8s + 2*(j&3) + (j>>2); 16B unit su=slot>>1, half=slot&1
                int c = k >> 3, ss = c >> 3, j = c & 7;
                int slot = (ss << 3) + ((j & 3) << 1) + (j >> 2);
                int su = slot >> 1, h = slot & 1;
                long long u32i = (((long long)(row >> 4) * (D >> 4) + su) * 16
                                  + (row & 15)) * 4 + h * 2 + ((k >> 2) & 1);
                xq[u32i] = (unsigned int)pk;
            }
        }
    } else {
        for (int k = threadIdx.x; k < D; k += 256) { float v = r[k]; s += v * v; }
    }
    for (int off = 32; off > 0; off >>= 1) {
        s += __shfl_down(s, off);
        amax = fmaxf(amax, __shfl_down(amax, off));
    }
    int wid = threadIdx.x >> 6, lane = threadIdx.x & 63;
    if (lane == 0) { red[wid] = s; redm[wid] = amax; }
    __syncthreads();
    if (threadIdx.x == 0) {
        float tot = red[0] + red[1] + red[2] + red[3];
        pn[row] = fmaxf(sqrtf(tot), EPSV);
        float bm = fmaxf(fmaxf(redm[0], redm[1]), fmaxf(redm[2], redm[3]));
        guard[row] = (do_conv && bm > ABS_GUARD) ? 1u : 0u;   // plain store
        if (row == 0) {
            *flag = (force_flag || (*n0p != 0)) ? 1u : 0u;
            *done = 0u;
        }
    }
}

// --- kernel 2: fp8 MFMA tri-check + last-block-done inline fallback ---
// 64x64 tile/block, 4 waves; wave w owns rows [r0+16w,+16) over full K.
// Superstep s (K=64): 1 A + 4 B 16B loads -> 8 fp8 MFMAs (K=32 each).
__global__ __launch_bounds__(256) void k_trimain(
    const unsigned int* __restrict__ xq, const float* __restrict__ pn,
    int B, int D, unsigned int* __restrict__ flag,
    unsigned int* __restrict__ done, const unsigned int* __restrict__ guard,
    const float* __restrict__ padrao, const float* __restrict__ erro,
    const float* __restrict__ protos0, const float* __restrict__ forca0,
    const int* __restrict__ n0p, const float* __restrict__ gainp,
    float* __restrict__ out, float* __restrict__ wprotos,
    float* __restrict__ wforca, float* __restrict__ wprotn,
    int runnable, int P) {
    // T1 bijective XCD swizzle (m204)
    int nblk = gridDim.x;
    int orig = blockIdx.x;
    int q8 = nblk >> 3, r8 = nblk & 7;
    int xcd = orig & 7, lin = orig >> 3;
    int bid = (xcd < r8 ? xcd * (q8 + 1) : r8 * (q8 + 1) + (xcd - r8) * q8) + lin;
    int ti = (int)((sqrtf(8.0f * (float)bid + 1.0f) - 1.0f) * 0.5f);
    while ((ti + 1) * (ti + 2) / 2 <= bid) ++ti;
    while (ti * (ti + 1) / 2 > bid) --ti;
    int tj = bid - ti * (ti + 1) / 2;
    int r0 = ti * 64, c0 = tj * 64;
    int tid = threadIdx.x;
    int w = tid >> 6, l = tid & 63;
    int l15 = l & 15, lhi = l >> 4;
    const int kchu = D >> 4;                // 16B units per row-panel
    const i64x2* gx = (const i64x2*)xq;
    long long rpan = (long long)((r0 >> 4) + w) * kchu;
    long long cpan0 = (long long)(c0 >> 4) * kchu;
    f32x4 acc[4] = {};
    int nss = D >> 6;                       // supersteps (K=64 each)
    for (int s = 0; s < nss; ++s) {
        int uc = (s << 2) + lhi;            // unit = 4s + lhi
        i64x2 a = gx[(rpan + uc) * 16 + l15];
        i64x2 b[4];
#pragma unroll
        for (int j = 0; j < 4; ++j)
            b[j] = gx[(cpan0 + (long long)j * kchu + uc) * 16 + l15];
#pragma unroll
        for (int j = 0; j < 4; ++j) {
            acc[j] = __builtin_amdgcn_mfma_f32_16x16x32_fp8_fp8(a[0], b[j][0], acc[j], 0, 0, 0);
            acc[j] = __builtin_amdgcn_mfma_f32_16x16x32_fp8_fp8(a[1], b[j][1], acc[j], 0, 0, 0);
        }
    }
    // threshold on registers; C layout (m89): col=l&15, row=lhi*4+r
    int trow = r0 + w * 16 + lhi * 4;
    float pnr[4];
#pragma unroll
    for (int r = 0; r < 4; ++r) {
        int t = trow + r;
        pnr[r] = (t < B) ? pn[t] : 1.0f;
    }
    unsigned int hit = 0;
#pragma unroll
    for (int j = 0; j < 4; ++j) {
        int jj = c0 + j * 16 + l15;
        float pc = (jj < B) ? pn[jj] : 1.0f;
#pragma unroll
        for (int r = 0; r < 4; ++r) {
            int t = trow + r;
            if (t < B && jj < B && t > jj && acc[j][r] >= CHECK_THRESH * pnr[r] * pc)
                hit = 1;
        }
    }
    if (hit) atomicOr(flag, 1u);

    // ---- last-block-done: merge the fallback node into this kernel ----
    __shared__ unsigned int lastsh;
    __syncthreads();                        // all block ORs issued
    if (tid == 0) {
        __threadfence();                    // release: this block's OR visible
        unsigned int ticket = atomicAdd(done, 1u);
        lastsh = (ticket == (unsigned int)(nblk - 1)) ? 1u : 0u;
    }
    __syncthreads();
    if (!lastsh) return;
    __threadfence();                        // acquire: see all blocks' ORs
    if (!runnable) return;
    __shared__ float rv[256];
    __shared__ int ri[256];
    __shared__ unsigned int fsh;
    if (tid == 0) fsh = atomicOr(flag, 0u); // atomic read (device scope)
    __syncthreads();
    unsigned int lf = 0;
    for (int i = tid; i < B; i += 256) lf |= guard[i];
    if (lf) atomicOr(&fsh, 1u);
    __syncthreads();
    if (fsh == 0u) return;
    fallback_body(256, tid, padrao, erro, protos0, forca0, n0p, gainp,
                  out, pn, wprotos, wforca, wprotn, B, D, P, rv, ri);
}

// ------------- fp32 tri-check (ragged-shape fallback path) -------------
__global__ __launch_bounds__(256) void k_tricheck(const float* __restrict__ padrao,
                                                  const float* __restrict__ pn,
                                                  int B, int D,
                                                  unsigned int* __restrict__ flag) {
    __shared__ float As[64][65];
    __shared__ float Bs[64][65];
    int bid = blockIdx.x;
    int ti = (int)((sqrtf(8.0f * (float)bid + 1.0f) - 1.0f) * 0.5f);
    while ((ti + 1) * (ti + 2) / 2 <= bid) ++ti;
    while (ti * (ti + 1) / 2 > bid) --ti;
    int tj = bid - ti * (ti + 1) / 2;
    int r0 = ti * 64, c0 = tj * 64;
    int tid = threadIdx.x;
    int ty = tid >> 4, tx = tid & 15;
    float acc[4][4] = {};
    for (int k0 = 0; k0 < D; k0 += 64) {
        for (int s = tid; s < 64 * 64; s += 256) {
            int rr = s >> 6, cc = s & 63;
            int gc = k0 + cc;
            int gr = r0 + rr;
            As[rr][cc] = (gr < B && gc < D) ? padrao[(long long)gr * D + gc] : 0.0f;
            gr = c0 + rr;
            Bs[rr][cc] = (gr < B && gc < D) ? padrao[(long long)gr * D + gc] : 0.0f;
        }
        __syncthreads();
        for (int kk = 0; kk < 64; ++kk) {
            float a[4], b[4];
#pragma unroll
            for (int i = 0; i < 4; ++i) a[i] = As[ty * 4 + i][kk];
#pragma unroll
            for (int j = 0; j < 4; ++j) b[j] = Bs[tx * 4 + j][kk];
#pragma unroll
            for (int i = 0; i < 4; ++i)
#pragma unroll
                for (int j = 0; j < 4; ++j) acc[i][j] += a[i] * b[j];
        }
        __syncthreads();
    }
    unsigned int hit = 0;
    for (int i = 0; i < 4; ++i)
        for (int j = 0; j < 4; ++j) {
            int t = r0 + ty * 4 + i, jj = c0 + tx * 4 + j;
            if (t < B && jj < B && t > jj) {
                if (acc[i][j] >= CHECK_THRESH * pn[t] * pn[jj]) hit = 1;
            }
        }
    if (hit) atomicOr(flag, 1u);
}

// ---------------- zero kernel (ragged path only) ----------------
__global__ __launch_bounds__(256) void k_zero_s(float* __restrict__ out, long long n) {
    long long i = (long long)blockIdx.x * blockDim.x + threadIdx.x;
    long long stride = (long long)gridDim.x * blockDim.x;
    for (; i < n; i += stride) out[i] = 0.0f;
}

// ------- ragged-path fallback node (runs iff flag|guard set) -------
__global__ __launch_bounds__(1024) void k_fallback(
    const float* __restrict__ padrao, const float* __restrict__ erro,
    const float* __restrict__ protos0, const float* __restrict__ forca0,
    const int* __restrict__ n0p, const float* __restrict__ gainp,
    float* __restrict__ out, const float* __restrict__ pn_arr,
    float* __restrict__ wprotos, float* __restrict__ wforca,
    float* __restrict__ wprotn, const unsigned int* __restrict__ flag,
    const unsigned int* __restrict__ guard, int nguard,
    int runnable, int B, int D, int P) {
    if (!runnable) return;
    const int tid = threadIdx.x;
    const int NT = blockDim.x;
    __shared__ unsigned int fsh;
    if (tid == 0) fsh = *flag;
    __syncthreads();
    unsigned int lf = 0;
    for (int i = tid; i < nguard; i += NT) lf |= guard[i];
    if (lf) atomicOr(&fsh, 1u);
    __syncthreads();
    if (fsh == 0u) return;
    __shared__ float rv[1024];
    __shared__ int ri[1024];
    fallback_body(NT, tid, padrao, erro, protos0, forca0, n0p, gainp,
                  out, pn_arr, wprotos, wforca, wprotn, B, D, P, rv, ri);
}

extern "C" void kernel_launch(void* const* d_in, const int* in_sizes, int n_in,
                              void* d_out, int out_size, void* d_ws, size_t ws_size,
                              hipStream_t stream) {
    const float* padrao  = (const float*)d_in[0];
    const float* erro    = (const float*)d_in[1];
    const float* protos0 = (const float*)d_in[2];
    const float* forca0  = (const float*)d_in[3];
    const int*   n0p     = (const int*)d_in[5];
    const float* gainp   = (const float*)d_in[6];
    const int B = in_sizes[1];
    const int D = (B > 0) ? in_sizes[0] / B : 0;
    const int P = in_sizes[3];

    char* ws = (char*)d_ws;
    unsigned int* flag = (unsigned int*)ws;
    unsigned int* done = (unsigned int*)(ws + 4);
    float* pn = (float*)(ws + 64);
    size_t off_guard = 64 + (size_t)B * 4;
    unsigned int* guard = (unsigned int*)(ws + off_guard);
    size_t off_xq = (off_guard + (size_t)B * 4 + 63) & ~(size_t)63;
    unsigned int* xq = (unsigned int*)(ws + off_xq);
    size_t off_protos = (off_xq + (size_t)B * (size_t)D + 63) & ~(size_t)63;  // fp8: B*D bytes
    float* wprotos = (float*)(ws + off_protos);
    size_t off_forca = off_protos + (size_t)P * (size_t)D * 4;
    float* wforca = (float*)(ws + off_forca);
    size_t off_protn = off_forca + (size_t)P * 4;
    float* wprotn = (float*)(ws + off_protn);
    size_t need_total = off_protn + (size_t)P * 4;
    size_t need_fast = off_xq + (size_t)B * (size_t)D;

    int runnable = (ws_size >= need_total) ? 1 : 0;
    int force_flag = (B > P) ? 1 : 0;
    int use_mfma = ((B % 64) == 0) && ((D % 128) == 0) && (ws_size >= need_fast)
                   && ((long long)out_size == (long long)B * D);

    int nT = (B + 63) / 64;
    int nblk = nT * (nT + 1) / 2;
    long long outN = (long long)out_size;

    if (use_mfma) {
        long long n4 = outN >> 2;   // outN = B*D, D%128==0 => divisible by 4
        k_prep<<<B, 256, 0, stream>>>(padrao, B, D, pn, xq, 1,
                                      (f32x4*)d_out, n4, 1, flag, done, guard,
                                      n0p, force_flag);
        k_trimain<<<nblk, 256, 0, stream>>>(xq, pn, B, D, flag, done, guard,
                                            padrao, erro, protos0, forca0,
                                            n0p, gainp, (float*)d_out,
                                            wprotos, wforca, wprotn,
                                            runnable, P);
    } else {
        hipMemsetAsync(ws, 0, 64 + (size_t)B * 4, stream);
        k_prep<<<B, 256, 0, stream>>>(padrao, B, D, pn, xq, 0,
                                      (f32x4*)d_out, 0, 0, flag, done, guard,
                                      n0p, force_flag);
        k_tricheck<<<nblk, 256, 0, stream>>>(padrao, pn, B, D, flag);
        int zb = (int)((outN + 255) / 256); if (zb > 2048) zb = 2048; if (zb < 1) zb = 1;
        k_zero_s<<<zb, 256, 0, stream>>>((float*)d_out, outN);
        k_fallback<<<1, 1024, 0, stream>>>(padrao, erro, protos0, forca0, n0p, gainp,
                                           (float*)d_out, pn, wprotos, wforca, wprotn,
                                           flag, guard, B, runnable, B, D, P);
    }
}

// Round 17
// 24.276 us; speedup vs baseline: 1.2898x; 1.2898x over previous
//
#include <hip/hip_runtime.h>
#include <hip/hip_bf16.h>
#include <math.h>

// Engram scan. Fast path: prove on-device that every step is a "create"
// (feedback == 0) and write zeros; exact sequential fallback otherwise.
//
// Soundness: n0==0 & B<=P => bank holds verbatim copies of earlier padrao
// rows and n<P always => every step creates unless a cos>=0.7 match exists
// among pairs (t, j<t). We flag at cos_q>=0.5 computed in fp8-e4m3 (RNE
// rel-err <=2^-4 => |cos_q-cos| <= ~0.135 with fp32 norms; 0.7-0.135 >
// 0.5 => conservative superset). Rows with any |x|>224 (e4m3 saturation)
// set guard[row] -> fallback. Also flagged: n0!=0, B>P. MFMA C-layout =
// m89 mapping; layout errors fail-safe (false flag -> exact fallback).
//
// r17 (r16 ticket-merge = +9.5us regression, reverted; r15=21.8 baseline):
// single change vs r15: trimain tile 64x64 -> 128x64, each wave owns
// 32 rows x 64 cols. Per superstep: 6 loads (2A+4B) -> 16 MFMAs
// (0.375 loads/MFMA, was 0.625). Total wave-load issues 169K -> 104K
// (-40%) -- attacks the measured L1/TA issue-count bound (r9: warm==cold;
// r11 swizzle null; r12 prefetch null). 272 blocks, no LDS, no barrier.
// 64x64 variant retained for B%64 shapes.

#define LIMIAR_SIM 0.7f
#define LIMIAR_NOVO 0.3f
#define LR 0.01f
#define EPSV 1e-8f
#define CHECK_THRESH 0.5f   // conservative vs 0.7 decision threshold
#define ABS_GUARD 224.0f    // |x| above this -> fp8 bound unsafe -> fallback

typedef __attribute__((ext_vector_type(4))) float f32x4;
typedef __attribute__((ext_vector_type(2))) long long i64x2;

// -- kernel 1: row norms + packed fp8 convert + nt zero-fill + guard row --
__global__ __launch_bounds__(256) void k_prep(const float* __restrict__ padrao,
                                              int B, int D, float* __restrict__ pn,
                                              unsigned int* __restrict__ xq,
                                              int do_conv,
                                              f32x4* __restrict__ out4,
                                              long long n4z, int do_zero,
                                              unsigned int* __restrict__ flag,
                                              unsigned int* __restrict__ guard,
                                              const int* __restrict__ n0p,
                                              int force_flag) {
    __shared__ float red[4];
    __shared__ float redm[4];
    int row = blockIdx.x;
    if (do_zero) {
        long long chunk = (n4z + gridDim.x - 1) / gridDim.x;
        long long zb = (long long)row * chunk;
        long long ze = zb + chunk; if (ze > n4z) ze = n4z;
        f32x4 z = {0.f, 0.f, 0.f, 0.f};
        for (long long i = zb + threadIdx.x; i < ze; i += 256)
            __builtin_nontemporal_store(z, &out4[i]);
    }
    const float* r = padrao + (long long)row * D;
    float s = 0.0f, amax = 0.0f;
    if ((D & 3) == 0) {
        for (int k = threadIdx.x * 4; k < D; k += 1024) {
            float4 v = *(const float4*)(r + k);
            s += v.x * v.x + v.y * v.y + v.z * v.z + v.w * v.w;
            amax = fmaxf(amax, fmaxf(fmaxf(fabsf(v.x), fabsf(v.y)),
                                     fmaxf(fabsf(v.z), fabsf(v.w))));
            if (do_conv) {
                // fp8 pack, 4 elems -> u32 (RNE via v_cvt_pk_fp8_f32)
                int pk = 0;
                pk = __builtin_amdgcn_cvt_pk_fp8_f32(v.x, v.y, pk, false);
                pk = __builtin_amdgcn_cvt_pk_fp8_f32(v.z, v.w, pk, true);
                // slot permutation: chunk c=k>>3 (8 fp8), s=c>>3, j=c&7
                // slot = 8s + 2*(j&3) + (j>>2); 16B unit su=slot>>1, half=slot&1
                int c = k >> 3, ss = c >> 3, j = c & 7;
                int slot = (ss << 3) + ((j & 3) << 1) + (j >> 2);
                int su = slot >> 1, h = slot & 1;
                long long u32i = (((long long)(row >> 4) * (D >> 4) + su) * 16
                                  + (row & 15)) * 4 + h * 2 + ((k >> 2) & 1);
                xq[u32i] = (unsigned int)pk;
            }
        }
    } else {
        for (int k = threadIdx.x; k < D; k += 256) { float v = r[k]; s += v * v; }
    }
    for (int off = 32; off > 0; off >>= 1) {
        s += __shfl_down(s, off);
        amax = fmaxf(amax, __shfl_down(amax, off));
    }
    int wid = threadIdx.x >> 6, lane = threadIdx.x & 63;
    if (lane == 0) { red[wid] = s; redm[wid] = amax; }
    __syncthreads();
    if (threadIdx.x == 0) {
        float tot = red[0] + red[1] + red[2] + red[3];
        pn[row] = fmaxf(sqrtf(tot), EPSV);
        float bm = fmaxf(fmaxf(redm[0], redm[1]), fmaxf(redm[2], redm[3]));
        guard[row] = (do_conv && bm > ABS_GUARD) ? 1u : 0u;   // plain store
        if (row == 0) *flag = (force_flag || (*n0p != 0)) ? 1u : 0u;
    }
}

// --- kernel 2a: fp8 MFMA tri-check, 128x64 tile, wave = 32 rows x 64 cols ---
// 4 waves M-split (32 rows each); superstep (K=64): 2A + 4B loads -> 16 MFMAs.
__global__ __launch_bounds__(256) void k_trimain128(const unsigned int* __restrict__ xq,
                                                    const float* __restrict__ pn,
                                                    int B, int D,
                                                    unsigned int* __restrict__ flag) {
    // T1 bijective XCD swizzle (m204)
    int nblk = gridDim.x;
    int orig = blockIdx.x;
    int q8 = nblk >> 3, r8 = nblk & 7;
    int xcd = orig & 7, lin = orig >> 3;
    int bid = (xcd < r8 ? xcd * (q8 + 1) : r8 * (q8 + 1) + (xcd - r8) * q8) + lin;
    // decode: cum(ti) = ti*(ti+1); tj in [0, 2ti+2)
    int ti = (int)((sqrtf(4.0f * (float)bid + 1.0f) - 1.0f) * 0.5f);
    while ((ti + 1) * (ti + 2) <= bid) ++ti;
    while (ti * (ti + 1) > bid) --ti;
    int tj = bid - ti * (ti + 1);
    int r0 = ti * 128, c0 = tj * 64;
    int tid = threadIdx.x;
    int w = tid >> 6, l = tid & 63;
    int l15 = l & 15, lhi = l >> 4;
    const int kchu = D >> 4;                // 16B units per row-panel
    const i64x2* gx = (const i64x2*)xq;
    long long rpan0 = (long long)((r0 >> 4) + 2 * w) * kchu;
    long long rpan1 = rpan0 + kchu;
    long long cpan0 = (long long)(c0 >> 4) * kchu;
    f32x4 acc0[4] = {}, acc1[4] = {};
    int nss = D >> 6;                       // supersteps (K=64 each)
    for (int s = 0; s < nss; ++s) {
        int uc = (s << 2) + lhi;            // unit = 4s + lhi
        i64x2 a0 = gx[(rpan0 + uc) * 16 + l15];
        i64x2 a1 = gx[(rpan1 + uc) * 16 + l15];
        i64x2 b[4];
#pragma unroll
        for (int j = 0; j < 4; ++j)
            b[j] = gx[(cpan0 + (long long)j * kchu + uc) * 16 + l15];
#pragma unroll
        for (int j = 0; j < 4; ++j) {
            acc0[j] = __builtin_amdgcn_mfma_f32_16x16x32_fp8_fp8(a0[0], b[j][0], acc0[j], 0, 0, 0);
            acc0[j] = __builtin_amdgcn_mfma_f32_16x16x32_fp8_fp8(a0[1], b[j][1], acc0[j], 0, 0, 0);
            acc1[j] = __builtin_amdgcn_mfma_f32_16x16x32_fp8_fp8(a1[0], b[j][0], acc1[j], 0, 0, 0);
            acc1[j] = __builtin_amdgcn_mfma_f32_16x16x32_fp8_fp8(a1[1], b[j][1], acc1[j], 0, 0, 0);
        }
    }
    // threshold on registers; C layout (m89): col=l&15, row=lhi*4+r
    int trow0 = r0 + w * 32 + lhi * 4;      // A panel 0 rows
    int trow1 = trow0 + 16;                 // A panel 1 rows
    unsigned int hit = 0;
#pragma unroll
    for (int j = 0; j < 4; ++j) {
        int jj = c0 + j * 16 + l15;
        float pc = (jj < B) ? pn[jj] : 1.0f;
#pragma unroll
        for (int r = 0; r < 4; ++r) {
            int t0 = trow0 + r, t1 = trow1 + r;
            if (t0 < B && jj < B && t0 > jj &&
                acc0[j][r] >= CHECK_THRESH * pn[t0] * pc) hit = 1;
            if (t1 < B && jj < B && t1 > jj &&
                acc1[j][r] >= CHECK_THRESH * pn[t1] * pc) hit = 1;
        }
    }
    if (hit) atomicOr(flag, 1u);
}

// --- kernel 2b: fp8 MFMA tri-check, 64x64 tile (r11/r15 variant, B%64) ---
__global__ __launch_bounds__(256) void k_trimain64(const unsigned int* __restrict__ xq,
                                                   const float* __restrict__ pn,
                                                   int B, int D,
                                                   unsigned int* __restrict__ flag) {
    int nblk = gridDim.x;
    int orig = blockIdx.x;
    int q8 = nblk >> 3, r8 = nblk & 7;
    int xcd = orig & 7, lin = orig >> 3;
    int bid = (xcd < r8 ? xcd * (q8 + 1) : r8 * (q8 + 1) + (xcd - r8) * q8) + lin;
    int ti = (int)((sqrtf(8.0f * (float)bid + 1.0f) - 1.0f) * 0.5f);
    while ((ti + 1) * (ti + 2) / 2 <= bid) ++ti;
    while (ti * (ti + 1) / 2 > bid) --ti;
    int tj = bid - ti * (ti + 1) / 2;
    int r0 = ti * 64, c0 = tj * 64;
    int tid = threadIdx.x;
    int w = tid >> 6, l = tid & 63;
    int l15 = l & 15, lhi = l >> 4;
    const int kchu = D >> 4;
    const i64x2* gx = (const i64x2*)xq;
    long long rpan = (long long)((r0 >> 4) + w) * kchu;
    long long cpan0 = (long long)(c0 >> 4) * kchu;
    f32x4 acc[4] = {};
    int nss = D >> 6;
    for (int s = 0; s < nss; ++s) {
        int uc = (s << 2) + lhi;
        i64x2 a = gx[(rpan + uc) * 16 + l15];
        i64x2 b[4];
#pragma unroll
        for (int j = 0; j < 4; ++j)
            b[j] = gx[(cpan0 + (long long)j * kchu + uc) * 16 + l15];
#pragma unroll
        for (int j = 0; j < 4; ++j) {
            acc[j] = __builtin_amdgcn_mfma_f32_16x16x32_fp8_fp8(a[0], b[j][0], acc[j], 0, 0, 0);
            acc[j] = __builtin_amdgcn_mfma_f32_16x16x32_fp8_fp8(a[1], b[j][1], acc[j], 0, 0, 0);
        }
    }
    int trow = r0 + w * 16 + lhi * 4;
    float pnr[4];
#pragma unroll
    for (int r = 0; r < 4; ++r) {
        int t = trow + r;
        pnr[r] = (t < B) ? pn[t] : 1.0f;
    }
    unsigned int hit = 0;
#pragma unroll
    for (int j = 0; j < 4; ++j) {
        int jj = c0 + j * 16 + l15;
        float pc = (jj < B) ? pn[jj] : 1.0f;
#pragma unroll
        for (int r = 0; r < 4; ++r) {
            int t = trow + r;
            if (t < B && jj < B && t > jj && acc[j][r] >= CHECK_THRESH * pnr[r] * pc)
                hit = 1;
        }
    }
    if (hit) atomicOr(flag, 1u);
}

// ------------- fp32 tri-check (ragged-shape fallback path) -------------
__global__ __launch_bounds__(256) void k_tricheck(const float* __restrict__ padrao,
                                                  const float* __restrict__ pn,
                                                  int B, int D,
                                                  unsigned int* __restrict__ flag) {
    __shared__ float As[64][65];
    __shared__ float Bs[64][65];
    int bid = blockIdx.x;
    int ti = (int)((sqrtf(8.0f * (float)bid + 1.0f) - 1.0f) * 0.5f);
    while ((ti + 1) * (ti + 2) / 2 <= bid) ++ti;
    while (ti * (ti + 1) / 2 > bid) --ti;
    int tj = bid - ti * (ti + 1) / 2;
    int r0 = ti * 64, c0 = tj * 64;
    int tid = threadIdx.x;
    int ty = tid >> 4, tx = tid & 15;
    float acc[4][4] = {};
    for (int k0 = 0; k0 < D; k0 += 64) {
        for (int s = tid; s < 64 * 64; s += 256) {
            int rr = s >> 6, cc = s & 63;
            int gc = k0 + cc;
            int gr = r0 + rr;
            As[rr][cc] = (gr < B && gc < D) ? padrao[(long long)gr * D + gc] : 0.0f;
            gr = c0 + rr;
            Bs[rr][cc] = (gr < B && gc < D) ? padrao[(long long)gr * D + gc] : 0.0f;
        }
        __syncthreads();
        for (int kk = 0; kk < 64; ++kk) {
            float a[4], b[4];
#pragma unroll
            for (int i = 0; i < 4; ++i) a[i] = As[ty * 4 + i][kk];
#pragma unroll
            for (int j = 0; j < 4; ++j) b[j] = Bs[tx * 4 + j][kk];
#pragma unroll
            for (int i = 0; i < 4; ++i)
#pragma unroll
                for (int j = 0; j < 4; ++j) acc[i][j] += a[i] * b[j];
        }
        __syncthreads();
    }
    unsigned int hit = 0;
    for (int i = 0; i < 4; ++i)
        for (int j = 0; j < 4; ++j) {
            int t = r0 + ty * 4 + i, jj = c0 + tx * 4 + j;
            if (t < B && jj < B && t > jj) {
                if (acc[i][j] >= CHECK_THRESH * pn[t] * pn[jj]) hit = 1;
            }
        }
    if (hit) atomicOr(flag, 1u);
}

// ---------------- zero kernel (ragged path only) ----------------
__global__ __launch_bounds__(256) void k_zero_s(float* __restrict__ out, long long n) {
    long long i = (long long)blockIdx.x * blockDim.x + threadIdx.x;
    long long stride = (long long)gridDim.x * blockDim.x;
    for (; i < n; i += stride) out[i] = 0.0f;
}

// ------- kernel 3: exact sequential fallback (runs iff flag|guard set) -------
__global__ __launch_bounds__(1024) void k_fallback(
    const float* __restrict__ padrao, const float* __restrict__ erro,
    const float* __restrict__ protos0, const float* __restrict__ forca0,
    const int* __restrict__ n0p, const float* __restrict__ gainp,
    float* __restrict__ out, const float* __restrict__ pn_arr,
    float* __restrict__ wprotos, float* __restrict__ wforca,
    float* __restrict__ wprotn, const unsigned int* __restrict__ flag,
    const unsigned int* __restrict__ guard, int nguard,
    int runnable, int B, int D, int P) {
    if (!runnable) return;
    const int tid = threadIdx.x;
    const int NT = blockDim.x;
    __shared__ unsigned int fsh;
    if (tid == 0) fsh = *flag;
    __syncthreads();
    unsigned int lf = 0;
    for (int i = tid; i < nguard; i += NT) lf |= guard[i];
    if (lf) atomicOr(&fsh, 1u);
    __syncthreads();
    if (fsh == 0u) return;
    __shared__ float rv[1024];
    __shared__ int ri[1024];
    for (long long i = tid; i < (long long)P * D; i += NT) wprotos[i] = protos0[i];
    for (int i = tid; i < P; i += NT) wforca[i] = forca0[i];
    __syncthreads();
    for (int j = tid; j < P; j += NT) {
        const float* r = wprotos + (long long)j * D;
        float s = 0.0f;
        for (int k = 0; k < D; ++k) s += r[k] * r[k];
        wprotn[j] = fmaxf(sqrtf(s), EPSV);
    }
    int n = *n0p;
    float gain = *gainp;
    __syncthreads();
    for (int t = 0; t < B; ++t) {
        const float* p = padrao + (long long)t * D;
        float pn = pn_arr[t];
        float best = -INFINITY; int bidx = 0;
        for (int j = tid; j < n; j += NT) {
            const float* r = wprotos + (long long)j * D;
            float d = 0.0f;
            for (int k = 0; k < D; ++k) d += r[k] * p[k];
            float sim = d / (wprotn[j] * pn);
            if (sim > best) { best = sim; bidx = j; }
        }
        rv[tid] = best; ri[tid] = bidx;
        __syncthreads();
        for (int off = NT >> 1; off > 0; off >>= 1) {
            if (tid < off) {
                float ov = rv[tid + off]; int oi = ri[tid + off];
                if (ov > rv[tid] || (ov == rv[tid] && oi < ri[tid])) { rv[tid] = ov; ri[tid] = oi; }
            }
            __syncthreads();
        }
        float max_sim = rv[0]; int idx = ri[0];
        __syncthreads();
        float err = erro[t];
        bool is_empty = (n == 0);
        bool do_reinf = (!is_empty) && (max_sim >= LIMIAR_SIM);
        bool do_create = is_empty || ((!do_reinf) && ((err > LIMIAR_NOVO) || (n < P)));
        if (do_create) {
            int cidx = n;
            if (n >= P) {
                float bv = INFINITY; int bi = 0;
                for (int j = tid; j < P; j += NT) {
                    float f = wforca[j];
                    if (f < bv) { bv = f; bi = j; }
                }
                rv[tid] = bv; ri[tid] = bi;
                __syncthreads();
                for (int off = NT >> 1; off > 0; off >>= 1) {
                    if (tid < off) {
                        float ov = rv[tid + off]; int oi = ri[tid + off];
                        if (ov < rv[tid] || (ov == rv[tid] && oi < ri[tid])) { rv[tid] = ov; ri[tid] = oi; }
                    }
                    __syncthreads();
                }
                cidx = ri[0];
                __syncthreads();
            }
            float* dst = wprotos + (long long)cidx * D;
            float* o = out + (long long)t * D;
            for (int k = tid; k < D; k += NT) { dst[k] = p[k]; o[k] = 0.0f; }
            if (tid == 0) { wforca[cidx] = 1.0f; wprotn[cidx] = pn; }
            if (n < P) n = n + 1;
        } else if (do_reinf) {
            float* dst = wprotos + (long long)idx * D;
            float fr_new = wforca[idx] + LR;
            float* o = out + (long long)t * D;
            float s2 = 0.0f;
            for (int k = tid; k < D; k += NT) {
                float np_ = (1.0f - LR) * dst[k] + LR * p[k];
                dst[k] = np_;
                o[k] = (np_ - p[k]) * fr_new * gain;
                s2 += np_ * np_;
            }
            rv[tid] = s2;
            __syncthreads();
            for (int off = NT >> 1; off > 0; off >>= 1) {
                if (tid < off) rv[tid] += rv[tid + off];
                __syncthreads();
            }
            if (tid == 0) { wforca[idx] = fr_new; wprotn[idx] = fmaxf(sqrtf(rv[0]), EPSV); }
        } else {
            const float* src = wprotos + (long long)idx * D;
            float fr = wforca[idx];
            float* o = out + (long long)t * D;
            for (int k = tid; k < D; k += NT) o[k] = (src[k] - p[k]) * fr * gain;
        }
        __syncthreads();
    }
}

extern "C" void kernel_launch(void* const* d_in, const int* in_sizes, int n_in,
                              void* d_out, int out_size, void* d_ws, size_t ws_size,
                              hipStream_t stream) {
    const float* padrao  = (const float*)d_in[0];
    const float* erro    = (const float*)d_in[1];
    const float* protos0 = (const float*)d_in[2];
    const float* forca0  = (const float*)d_in[3];
    const int*   n0p     = (const int*)d_in[5];
    const float* gainp   = (const float*)d_in[6];
    const int B = in_sizes[1];
    const int D = (B > 0) ? in_sizes[0] / B : 0;
    const int P = in_sizes[3];

    char* ws = (char*)d_ws;
    unsigned int* flag = (unsigned int*)ws;
    float* pn = (float*)(ws + 64);
    size_t off_guard = 64 + (size_t)B * 4;
    unsigned int* guard = (unsigned int*)(ws + off_guard);
    size_t off_xq = (off_guard + (size_t)B * 4 + 63) & ~(size_t)63;
    unsigned int* xq = (unsigned int*)(ws + off_xq);
    size_t off_protos = (off_xq + (size_t)B * (size_t)D + 63) & ~(size_t)63;  // fp8: B*D bytes
    float* wprotos = (float*)(ws + off_protos);
    size_t off_forca = off_protos + (size_t)P * (size_t)D * 4;
    float* wforca = (float*)(ws + off_forca);
    size_t off_protn = off_forca + (size_t)P * 4;
    float* wprotn = (float*)(ws + off_protn);
    size_t need_total = off_protn + (size_t)P * 4;
    size_t need_fast = off_xq + (size_t)B * (size_t)D;

    int runnable = (ws_size >= need_total) ? 1 : 0;
    int force_flag = (B > P) ? 1 : 0;
    int use_mfma = ((B % 64) == 0) && ((D % 128) == 0) && (ws_size >= need_fast)
                   && ((long long)out_size == (long long)B * D);

    long long outN = (long long)out_size;

    if (use_mfma) {
        long long n4 = outN >> 2;   // outN = B*D, D%128==0 => divisible by 4
        k_prep<<<B, 256, 0, stream>>>(padrao, B, D, pn, xq, 1,
                                      (f32x4*)d_out, n4, 1, flag, guard, n0p, force_flag);
        if ((B % 128) == 0) {
            int nRT = B / 128;
            int nblk = nRT * (nRT + 1);   // tiles with tj <= 2ti+1
            k_trimain128<<<nblk, 256, 0, stream>>>(xq, pn, B, D, flag);
        } else {
            int nT = B / 64;
            int nblk = nT * (nT + 1) / 2;
            k_trimain64<<<nblk, 256, 0, stream>>>(xq, pn, B, D, flag);
        }
        k_fallback<<<1, 1024, 0, stream>>>(padrao, erro, protos0, forca0, n0p, gainp,
                                           (float*)d_out, pn, wprotos, wforca, wprotn,
                                           flag, guard, B, runnable, B, D, P);
    } else {
        hipMemsetAsync(ws, 0, 64 + (size_t)B * 4, stream);
        k_prep<<<B, 256, 0, stream>>>(padrao, B, D, pn, xq, 0,
                                      (f32x4*)d_out, 0, 0, flag, guard, n0p, force_flag);
        int nT = (B + 63) / 64;
        int nblk = nT * (nT + 1) / 2;
        k_tricheck<<<nblk, 256, 0, stream>>>(padrao, pn, B, D, flag);
        int zb = (int)((outN + 255) / 256); if (zb > 2048) zb = 2048; if (zb < 1) zb = 1;
        k_zero_s<<<zb, 256, 0, stream>>>((float*)d_out, outN);
        k_fallback<<<1, 1024, 0, stream>>>(padrao, erro, protos0, forca0, n0p, gainp,
                                           (float*)d_out, pn, wprotos, wforca, wprotn,
                                           flag, guard, B, runnable, B, D, P);
    }
}

// Round 18
// 21.809 us; speedup vs baseline: 1.4356x; 1.1131x over previous
//
#include <hip/hip_runtime.h>
#include <hip/hip_bf16.h>
#include <math.h>

// Engram scan. Fast path: prove on-device that every step is a "create"
// (feedback == 0) and write zeros; exact sequential fallback otherwise.
//
// Soundness: n0==0 & B<=P => bank holds verbatim copies of earlier padrao
// rows and n<P always => every step creates unless a cos>=0.7 match exists
// among pairs (t, j<t). We flag at cos_q>=0.5 computed in fp8-e4m3 (RNE
// rel-err <=2^-4 => |cos_q-cos| <= ~0.135 with fp32 norms; 0.7-0.135 >
// 0.5 => conservative superset). Rows with any |x|>224 (e4m3 saturation)
// set guard[row] -> fallback. Also flagged: n0!=0, B>P. MFMA C-layout =
// m89 mapping; layout errors fail-safe (false flag -> exact fallback).
//
// r18 = REVERT to r15 exactly (measured optimum, 21.8us). The r15 config:
//  * 3 nodes: prep (norms+fp8 pack+nt zero-fill+guard), trimain64 (fp8
//    MFMA tri-check, M-split, XCD swizzle), fallback (early-exit).
//  * Sweep results that bracket this optimum: trimain prefetch null (r12),
//    swizzle null (r11), 8-wave K-split -14% (r8), 128x64 tile -11% (r17),
//    warm==cold (r9) => trimain ~11us ~ 75% of L1-return-BW ceiling at
//    2 waves/SIMD. Node merges: cooperative -5x (r14), ticket +9.5us (r16);
//    node removal via restructuring helped only when no new sync added (r15).

#define LIMIAR_SIM 0.7f
#define LIMIAR_NOVO 0.3f
#define LR 0.01f
#define EPSV 1e-8f
#define CHECK_THRESH 0.5f   // conservative vs 0.7 decision threshold
#define ABS_GUARD 224.0f    // |x| above this -> fp8 bound unsafe -> fallback

typedef __attribute__((ext_vector_type(4))) float f32x4;
typedef __attribute__((ext_vector_type(2))) long long i64x2;

// -- kernel 1: row norms + packed fp8 convert + nt zero-fill + guard row --
__global__ __launch_bounds__(256) void k_prep(const float* __restrict__ padrao,
                                              int B, int D, float* __restrict__ pn,
                                              unsigned int* __restrict__ xq,
                                              int do_conv,
                                              f32x4* __restrict__ out4,
                                              long long n4z, int do_zero,
                                              unsigned int* __restrict__ flag,
                                              unsigned int* __restrict__ guard,
                                              const int* __restrict__ n0p,
                                              int force_flag) {
    __shared__ float red[4];
    __shared__ float redm[4];
    int row = blockIdx.x;
    if (do_zero) {
        long long chunk = (n4z + gridDim.x - 1) / gridDim.x;
        long long zb = (long long)row * chunk;
        long long ze = zb + chunk; if (ze > n4z) ze = n4z;
        f32x4 z = {0.f, 0.f, 0.f, 0.f};
        for (long long i = zb + threadIdx.x; i < ze; i += 256)
            __builtin_nontemporal_store(z, &out4[i]);
    }
    const float* r = padrao + (long long)row * D;
    float s = 0.0f, amax = 0.0f;
    if ((D & 3) == 0) {
        for (int k = threadIdx.x * 4; k < D; k += 1024) {
            float4 v = *(const float4*)(r + k);
            s += v.x * v.x + v.y * v.y + v.z * v.z + v.w * v.w;
            amax = fmaxf(amax, fmaxf(fmaxf(fabsf(v.x), fabsf(v.y)),
                                     fmaxf(fabsf(v.z), fabsf(v.w))));
            if (do_conv) {
                // fp8 pack, 4 elems -> u32 (RNE via v_cvt_pk_fp8_f32)
                int pk = 0;
                pk = __builtin_amdgcn_cvt_pk_fp8_f32(v.x, v.y, pk, false);
                pk = __builtin_amdgcn_cvt_pk_fp8_f32(v.z, v.w, pk, true);
                // slot permutation: chunk c=k>>3 (8 fp8), s=c>>3, j=c&7
                // slot = 8s + 2*(j&3) + (j>>2); 16B unit su=slot>>1, half=slot&1
                int c = k >> 3, ss = c >> 3, j = c & 7;
                int slot = (ss << 3) + ((j & 3) << 1) + (j >> 2);
                int su = slot >> 1, h = slot & 1;
                long long u32i = (((long long)(row >> 4) * (D >> 4) + su) * 16
                                  + (row & 15)) * 4 + h * 2 + ((k >> 2) & 1);
                xq[u32i] = (unsigned int)pk;
            }
        }
    } else {
        for (int k = threadIdx.x; k < D; k += 256) { float v = r[k]; s += v * v; }
    }
    for (int off = 32; off > 0; off >>= 1) {
        s += __shfl_down(s, off);
        amax = fmaxf(amax, __shfl_down(amax, off));
    }
    int wid = threadIdx.x >> 6, lane = threadIdx.x & 63;
    if (lane == 0) { red[wid] = s; redm[wid] = amax; }
    __syncthreads();
    if (threadIdx.x == 0) {
        float tot = red[0] + red[1] + red[2] + red[3];
        pn[row] = fmaxf(sqrtf(tot), EPSV);
        float bm = fmaxf(fmaxf(redm[0], redm[1]), fmaxf(redm[2], redm[3]));
        guard[row] = (do_conv && bm > ABS_GUARD) ? 1u : 0u;   // plain store
        if (row == 0) *flag = (force_flag || (*n0p != 0)) ? 1u : 0u;
    }
}

// ------- kernel 2: fp8 MFMA tri-check, M-split, XCD-swizzled blocks -------
// 64x64 tile/block, 4 waves; wave w owns rows [r0+16w,+16) over full K.
// Superstep s (K=64): 1 A + 4 B 16B loads -> 8 fp8 MFMAs (K=32 each).
__global__ __launch_bounds__(256) void k_trimain(const unsigned int* __restrict__ xq,
                                                 const float* __restrict__ pn,
                                                 int B, int D,
                                                 unsigned int* __restrict__ flag) {
    // T1 bijective XCD swizzle (m204)
    int nblk = gridDim.x;
    int orig = blockIdx.x;
    int q8 = nblk >> 3, r8 = nblk & 7;
    int xcd = orig & 7, lin = orig >> 3;
    int bid = (xcd < r8 ? xcd * (q8 + 1) : r8 * (q8 + 1) + (xcd - r8) * q8) + lin;
    int ti = (int)((sqrtf(8.0f * (float)bid + 1.0f) - 1.0f) * 0.5f);
    while ((ti + 1) * (ti + 2) / 2 <= bid) ++ti;
    while (ti * (ti + 1) / 2 > bid) --ti;
    int tj = bid - ti * (ti + 1) / 2;
    int r0 = ti * 64, c0 = tj * 64;
    int tid = threadIdx.x;
    int w = tid >> 6, l = tid & 63;
    int l15 = l & 15, lhi = l >> 4;
    const int kchu = D >> 4;                // 16B units per row-panel
    const i64x2* gx = (const i64x2*)xq;
    long long rpan = (long long)((r0 >> 4) + w) * kchu;
    long long cpan0 = (long long)(c0 >> 4) * kchu;
    f32x4 acc[4] = {};
    int nss = D >> 6;                       // supersteps (K=64 each)
    for (int s = 0; s < nss; ++s) {
        int uc = (s << 2) + lhi;            // unit = 4s + lhi
        i64x2 a = gx[(rpan + uc) * 16 + l15];
        i64x2 b[4];
#pragma unroll
        for (int j = 0; j < 4; ++j)
            b[j] = gx[(cpan0 + (long long)j * kchu + uc) * 16 + l15];
#pragma unroll
        for (int j = 0; j < 4; ++j) {
            acc[j] = __builtin_amdgcn_mfma_f32_16x16x32_fp8_fp8(a[0], b[j][0], acc[j], 0, 0, 0);
            acc[j] = __builtin_amdgcn_mfma_f32_16x16x32_fp8_fp8(a[1], b[j][1], acc[j], 0, 0, 0);
        }
    }
    // threshold on registers; C layout (m89): col=l&15, row=lhi*4+r
    int trow = r0 + w * 16 + lhi * 4;
    float pnr[4];
#pragma unroll
    for (int r = 0; r < 4; ++r) {
        int t = trow + r;
        pnr[r] = (t < B) ? pn[t] : 1.0f;
    }
    unsigned int hit = 0;
#pragma unroll
    for (int j = 0; j < 4; ++j) {
        int jj = c0 + j * 16 + l15;
        float pc = (jj < B) ? pn[jj] : 1.0f;
#pragma unroll
        for (int r = 0; r < 4; ++r) {
            int t = trow + r;
            if (t < B && jj < B && t > jj && acc[j][r] >= CHECK_THRESH * pnr[r] * pc)
                hit = 1;
        }
    }
    if (hit) atomicOr(flag, 1u);
}

// ------------- fp32 tri-check (ragged-shape fallback path) -------------
__global__ __launch_bounds__(256) void k_tricheck(const float* __restrict__ padrao,
                                                  const float* __restrict__ pn,
                                                  int B, int D,
                                                  unsigned int* __restrict__ flag) {
    __shared__ float As[64][65];
    __shared__ float Bs[64][65];
    int bid = blockIdx.x;
    int ti = (int)((sqrtf(8.0f * (float)bid + 1.0f) - 1.0f) * 0.5f);
    while ((ti + 1) * (ti + 2) / 2 <= bid) ++ti;
    while (ti * (ti + 1) / 2 > bid) --ti;
    int tj = bid - ti * (ti + 1) / 2;
    int r0 = ti * 64, c0 = tj * 64;
    int tid = threadIdx.x;
    int ty = tid >> 4, tx = tid & 15;
    float acc[4][4] = {};
    for (int k0 = 0; k0 < D; k0 += 64) {
        for (int s = tid; s < 64 * 64; s += 256) {
            int rr = s >> 6, cc = s & 63;
            int gc = k0 + cc;
            int gr = r0 + rr;
            As[rr][cc] = (gr < B && gc < D) ? padrao[(long long)gr * D + gc] : 0.0f;
            gr = c0 + rr;
            Bs[rr][cc] = (gr < B && gc < D) ? padrao[(long long)gr * D + gc] : 0.0f;
        }
        __syncthreads();
        for (int kk = 0; kk < 64; ++kk) {
            float a[4], b[4];
#pragma unroll
            for (int i = 0; i < 4; ++i) a[i] = As[ty * 4 + i][kk];
#pragma unroll
            for (int j = 0; j < 4; ++j) b[j] = Bs[tx * 4 + j][kk];
#pragma unroll
            for (int i = 0; i < 4; ++i)
#pragma unroll
                for (int j = 0; j < 4; ++j) acc[i][j] += a[i] * b[j];
        }
        __syncthreads();
    }
    unsigned int hit = 0;
    for (int i = 0; i < 4; ++i)
        for (int j = 0; j < 4; ++j) {
            int t = r0 + ty * 4 + i, jj = c0 + tx * 4 + j;
            if (t < B && jj < B && t > jj) {
                if (acc[i][j] >= CHECK_THRESH * pn[t] * pn[jj]) hit = 1;
            }
        }
    if (hit) atomicOr(flag, 1u);
}

// ---------------- zero kernel (ragged path only) ----------------
__global__ __launch_bounds__(256) void k_zero_s(float* __restrict__ out, long long n) {
    long long i = (long long)blockIdx.x * blockDim.x + threadIdx.x;
    long long stride = (long long)gridDim.x * blockDim.x;
    for (; i < n; i += stride) out[i] = 0.0f;
}

// ------- kernel 3: exact sequential fallback (runs iff flag|guard set) -------
__global__ __launch_bounds__(1024) void k_fallback(
    const float* __restrict__ padrao, const float* __restrict__ erro,
    const float* __restrict__ protos0, const float* __restrict__ forca0,
    const int* __restrict__ n0p, const float* __restrict__ gainp,
    float* __restrict__ out, const float* __restrict__ pn_arr,
    float* __restrict__ wprotos, float* __restrict__ wforca,
    float* __restrict__ wprotn, const unsigned int* __restrict__ flag,
    const unsigned int* __restrict__ guard, int nguard,
    int runnable, int B, int D, int P) {
    if (!runnable) return;
    const int tid = threadIdx.x;
    const int NT = blockDim.x;
    __shared__ unsigned int fsh;
    if (tid == 0) fsh = *flag;
    __syncthreads();
    unsigned int lf = 0;
    for (int i = tid; i < nguard; i += NT) lf |= guard[i];
    if (lf) atomicOr(&fsh, 1u);
    __syncthreads();
    if (fsh == 0u) return;
    __shared__ float rv[1024];
    __shared__ int ri[1024];
    for (long long i = tid; i < (long long)P * D; i += NT) wprotos[i] = protos0[i];
    for (int i = tid; i < P; i += NT) wforca[i] = forca0[i];
    __syncthreads();
    for (int j = tid; j < P; j += NT) {
        const float* r = wprotos + (long long)j * D;
        float s = 0.0f;
        for (int k = 0; k < D; ++k) s += r[k] * r[k];
        wprotn[j] = fmaxf(sqrtf(s), EPSV);
    }
    int n = *n0p;
    float gain = *gainp;
    __syncthreads();
    for (int t = 0; t < B; ++t) {
        const float* p = padrao + (long long)t * D;
        float pn = pn_arr[t];
        float best = -INFINITY; int bidx = 0;
        for (int j = tid; j < n; j += NT) {
            const float* r = wprotos + (long long)j * D;
            float d = 0.0f;
            for (int k = 0; k < D; ++k) d += r[k] * p[k];
            float sim = d / (wprotn[j] * pn);
            if (sim > best) { best = sim; bidx = j; }
        }
        rv[tid] = best; ri[tid] = bidx;
        __syncthreads();
        for (int off = NT >> 1; off > 0; off >>= 1) {
            if (tid < off) {
                float ov = rv[tid + off]; int oi = ri[tid + off];
                if (ov > rv[tid] || (ov == rv[tid] && oi < ri[tid])) { rv[tid] = ov; ri[tid] = oi; }
            }
            __syncthreads();
        }
        float max_sim = rv[0]; int idx = ri[0];
        __syncthreads();
        float err = erro[t];
        bool is_empty = (n == 0);
        bool do_reinf = (!is_empty) && (max_sim >= LIMIAR_SIM);
        bool do_create = is_empty || ((!do_reinf) && ((err > LIMIAR_NOVO) || (n < P)));
        if (do_create) {
            int cidx = n;
            if (n >= P) {
                float bv = INFINITY; int bi = 0;
                for (int j = tid; j < P; j += NT) {
                    float f = wforca[j];
                    if (f < bv) { bv = f; bi = j; }
                }
                rv[tid] = bv; ri[tid] = bi;
                __syncthreads();
                for (int off = NT >> 1; off > 0; off >>= 1) {
                    if (tid < off) {
                        float ov = rv[tid + off]; int oi = ri[tid + off];
                        if (ov < rv[tid] || (ov == rv[tid] && oi < ri[tid])) { rv[tid] = ov; ri[tid] = oi; }
                    }
                    __syncthreads();
                }
                cidx = ri[0];
                __syncthreads();
            }
            float* dst = wprotos + (long long)cidx * D;
            float* o = out + (long long)t * D;
            for (int k = tid; k < D; k += NT) { dst[k] = p[k]; o[k] = 0.0f; }
            if (tid == 0) { wforca[cidx] = 1.0f; wprotn[cidx] = pn; }
            if (n < P) n = n + 1;
        } else if (do_reinf) {
            float* dst = wprotos + (long long)idx * D;
            float fr_new = wforca[idx] + LR;
            float* o = out + (long long)t * D;
            float s2 = 0.0f;
            for (int k = tid; k < D; k += NT) {
                float np_ = (1.0f - LR) * dst[k] + LR * p[k];
                dst[k] = np_;
                o[k] = (np_ - p[k]) * fr_new * gain;
                s2 += np_ * np_;
            }
            rv[tid] = s2;
            __syncthreads();
            for (int off = NT >> 1; off > 0; off >>= 1) {
                if (tid < off) rv[tid] += rv[tid + off];
                __syncthreads();
            }
            if (tid == 0) { wforca[idx] = fr_new; wprotn[idx] = fmaxf(sqrtf(rv[0]), EPSV); }
        } else {
            const float* src = wprotos + (long long)idx * D;
            float fr = wforca[idx];
            float* o = out + (long long)t * D;
            for (int k = tid; k < D; k += NT) o[k] = (src[k] - p[k]) * fr * gain;
        }
        __syncthreads();
    }
}

extern "C" void kernel_launch(void* const* d_in, const int* in_sizes, int n_in,
                              void* d_out, int out_size, void* d_ws, size_t ws_size,
                              hipStream_t stream) {
    const float* padrao  = (const float*)d_in[0];
    const float* erro    = (const float*)d_in[1];
    const float* protos0 = (const float*)d_in[2];
    const float* forca0  = (const float*)d_in[3];
    const int*   n0p     = (const int*)d_in[5];
    const float* gainp   = (const float*)d_in[6];
    const int B = in_sizes[1];
    const int D = (B > 0) ? in_sizes[0] / B : 0;
    const int P = in_sizes[3];

    char* ws = (char*)d_ws;
    unsigned int* flag = (unsigned int*)ws;
    float* pn = (float*)(ws + 64);
    size_t off_guard = 64 + (size_t)B * 4;
    unsigned int* guard = (unsigned int*)(ws + off_guard);
    size_t off_xq = (off_guard + (size_t)B * 4 + 63) & ~(size_t)63;
    unsigned int* xq = (unsigned int*)(ws + off_xq);
    size_t off_protos = (off_xq + (size_t)B * (size_t)D + 63) & ~(size_t)63;  // fp8: B*D bytes
    float* wprotos = (float*)(ws + off_protos);
    size_t off_forca = off_protos + (size_t)P * (size_t)D * 4;
    float* wforca = (float*)(ws + off_forca);
    size_t off_protn = off_forca + (size_t)P * 4;
    float* wprotn = (float*)(ws + off_protn);
    size_t need_total = off_protn + (size_t)P * 4;
    size_t need_fast = off_xq + (size_t)B * (size_t)D;

    int runnable = (ws_size >= need_total) ? 1 : 0;
    int force_flag = (B > P) ? 1 : 0;
    int use_mfma = ((B % 64) == 0) && ((D % 128) == 0) && (ws_size >= need_fast)
                   && ((long long)out_size == (long long)B * D);

    int nT = (B + 63) / 64;
    int nblk = nT * (nT + 1) / 2;
    long long outN = (long long)out_size;

    if (use_mfma) {
        long long n4 = outN >> 2;   // outN = B*D, D%128==0 => divisible by 4
        k_prep<<<B, 256, 0, stream>>>(padrao, B, D, pn, xq, 1,
                                      (f32x4*)d_out, n4, 1, flag, guard, n0p, force_flag);
        k_trimain<<<nblk, 256, 0, stream>>>(xq, pn, B, D, flag);
        k_fallback<<<1, 1024, 0, stream>>>(padrao, erro, protos0, forca0, n0p, gainp,
                                           (float*)d_out, pn, wprotos, wforca, wprotn,
                                           flag, guard, B, runnable, B, D, P);
    } else {
        hipMemsetAsync(ws, 0, 64 + (size_t)B * 4, stream);
        k_prep<<<B, 256, 0, stream>>>(padrao, B, D, pn, xq, 0,
                                      (f32x4*)d_out, 0, 0, flag, guard, n0p, force_flag);
        k_tricheck<<<nblk, 256, 0, stream>>>(padrao, pn, B, D, flag);
        int zb = (int)((outN + 255) / 256); if (zb > 2048) zb = 2048; if (zb < 1) zb = 1;
        k_zero_s<<<zb, 256, 0, stream>>>((float*)d_out, outN);
        k_fallback<<<1, 1024, 0, stream>>>(padrao, erro, protos0, forca0, n0p, gainp,
                                           (float*)d_out, pn, wprotos, wforca, wprotn,
                                           flag, guard, B, runnable, B, D, P);
    }
}